// Round 1
// 728.254 us; speedup vs baseline: 1.0231x; 1.0231x over previous
//
#include <hip/hip_runtime.h>
#include <hip/hip_bf16.h>

#define B_  16
#define S_  4096
#define D_  512
#define M_  2048
#define ROWS (B_ * S_)   // 65536
#define N3D  (3 * D_)    // 1536

typedef __attribute__((ext_vector_type(8))) short bf16x8;
typedef __attribute__((ext_vector_type(4))) float f32x4;

// ---------------- conversions ----------------

__global__ __launch_bounds__(256) void cvt_x_kernel(const float* __restrict__ x,
                                                    __hip_bfloat16* __restrict__ xb) {
    long i = (long)blockIdx.x * 256 + threadIdx.x;   // i in [0, ROWS*D_/8)
    const float4* x4 = (const float4*)x;
    float4 a = x4[2 * i], b = x4[2 * i + 1];
    union { __hip_bfloat16 h[8]; int4 v; } u;
    u.h[0] = __float2bfloat16(a.x); u.h[1] = __float2bfloat16(a.y);
    u.h[2] = __float2bfloat16(a.z); u.h[3] = __float2bfloat16(a.w);
    u.h[4] = __float2bfloat16(b.x); u.h[5] = __float2bfloat16(b.y);
    u.h[6] = __float2bfloat16(b.z); u.h[7] = __float2bfloat16(b.w);
    ((int4*)xb)[i] = u.v;
}

// W_qkv (D x 3D, row-major) -> Wt (3D x D) bf16, transposed.
// LDS 32x33 tile transpose: coalesced reads AND writes (old version read at
// stride 6KB -> 16x overfetch).
__global__ __launch_bounds__(256) void cvt_w_kernel(const float* __restrict__ w,
                                                    __hip_bfloat16* __restrict__ wt) {
    __shared__ float t[32][33];
    int n0 = blockIdx.x * 32;       // 48 chunks over N3D
    int k0 = blockIdx.y * 32;       // 16 chunks over D
    int c = threadIdx.x & 31, r = threadIdx.x >> 5;   // r in 0..7
    #pragma unroll
    for (int i = 0; i < 4; i++)
        t[r + 8 * i][c] = w[(long)(k0 + r + 8 * i) * N3D + n0 + c];
    __syncthreads();
    #pragma unroll
    for (int i = 0; i < 4; i++)
        wt[(long)(n0 + r + 8 * i) * 512 + k0 + c] = __float2bfloat16(t[c][r + 8 * i]);
}

// ---------------- qkv GEMM ----------------
// C[65536 x 1536] = Xb[65536 x 512] @ Wt^T + bias; scatter cols to q/k (fp32), v (bf16)
// m97 structure: 128x128 tile, BK=32, global_load_lds width-16, 2-barrier loop.
// LDS swizzle (both-sides-or-neither, rule #21): LDS dest linear, global SOURCE
// pre-permuted by the involution byte ^= ((byte>>7)&3)<<4, ds_read uses the same
// permutation -> 16-lane column-slice reads hit 8 distinct 4-bank groups (2-way, free).

__device__ __forceinline__ void gload16(const __hip_bfloat16* g, __hip_bfloat16* l) {
    __builtin_amdgcn_global_load_lds(
        (const __attribute__((address_space(1))) unsigned int*)g,
        (__attribute__((address_space(3))) unsigned int*)l, 16, 0, 0);
}

__global__ __launch_bounds__(256) void gemm_qkv_kernel(
    const __hip_bfloat16* __restrict__ Xb,
    const __hip_bfloat16* __restrict__ Wt,
    const float* __restrict__ bias,
    float* __restrict__ qout, float* __restrict__ kout,
    __hip_bfloat16* __restrict__ vout)
{
    __shared__ __attribute__((aligned(128))) __hip_bfloat16 As[128 * 32];
    __shared__ __attribute__((aligned(128))) __hip_bfloat16 Bs[128 * 32];

    const int tid  = threadIdx.x;
    const int wave = tid >> 6, lane = tid & 63;

    // bijective XCD swizzle: 6144 blocks, 768 per XCD; within an XCD, n varies
    // fastest so the 12 blocks sharing an A-panel are L2-temporally adjacent.
    int bid = blockIdx.x;
    int swz = (bid & 7) * 768 + (bid >> 3);
    const int m0 = (swz / 12) * 128;
    const int n0 = (swz % 12) * 128;

    const int wm   = (wave >> 1) * 64, wn = (wave & 1) * 64;
    const int quad = lane >> 4, l16 = lane & 15;

    // Staging geometry: per K-step the A tile is 128x32 bf16 = 8192 B.
    // One gload16 issue = 4 waves x 64 lanes x 16 B = 4096 B -> 2 issues per operand.
    // beta = linear LDS byte offset = issue*4096 + wave*1024 + lane*16.
    const int beta0 = wave * 1024 + lane * 16;
    const int row0  = beta0 >> 6;                                // 0..63
    const int cb0   = (beta0 & 63) ^ (((beta0 >> 7) & 3) << 4);  // swizzled src col-byte
    // beta1 = beta0 + 4096: row1 = row0+64, (row1>>1)&3 == (row0>>1)&3 -> same cb.

    const __hip_bfloat16* aSrc0 = Xb + (long)(m0 + row0)      * 512 + (cb0 >> 1);
    const __hip_bfloat16* aSrc1 = Xb + (long)(m0 + row0 + 64) * 512 + (cb0 >> 1);
    const __hip_bfloat16* bSrc0 = Wt + (long)(n0 + row0)      * 512 + (cb0 >> 1);
    const __hip_bfloat16* bSrc1 = Wt + (long)(n0 + row0 + 64) * 512 + (cb0 >> 1);
    __hip_bfloat16* aDst0 = As + (beta0 >> 1);
    __hip_bfloat16* aDst1 = As + ((beta0 + 4096) >> 1);
    __hip_bfloat16* bDst0 = Bs + (beta0 >> 1);
    __hip_bfloat16* bDst1 = Bs + ((beta0 + 4096) >> 1);

    // Fragment ds_read element offsets (fixed across K-steps): row*32 + (quad ^ ((row>>1)&3))*8
    int aoff[4], boff[4];
    #pragma unroll
    for (int t = 0; t < 4; t++) {
        int ra = wm + t * 16 + l16;
        aoff[t] = ra * 32 + ((quad ^ ((ra >> 1) & 3)) << 3);
        int rb = wn + t * 16 + l16;
        boff[t] = rb * 32 + ((quad ^ ((rb >> 1) & 3)) << 3);
    }

    f32x4 acc[4][4] = {};

    for (int k0 = 0; k0 < 512; k0 += 32) {
        gload16(aSrc0 + k0, aDst0);
        gload16(aSrc1 + k0, aDst1);
        gload16(bSrc0 + k0, bDst0);
        gload16(bSrc1 + k0, bDst1);
        __syncthreads();   // drains vmcnt -> LDS tile complete for all waves

        bf16x8 af[4], bf[4];
        #pragma unroll
        for (int t = 0; t < 4; t++) {
            af[t] = *(const bf16x8*)&As[aoff[t]];
            bf[t] = *(const bf16x8*)&Bs[boff[t]];
        }
        #pragma unroll
        for (int mt = 0; mt < 4; mt++)
            #pragma unroll
            for (int nt = 0; nt < 4; nt++)
                acc[mt][nt] = __builtin_amdgcn_mfma_f32_16x16x32_bf16(
                    af[mt], bf[nt], acc[mt][nt], 0, 0, 0);

        __syncthreads();   // all ds_reads done before next tile overwrites
    }

    #pragma unroll
    for (int mt = 0; mt < 4; mt++) {
        #pragma unroll
        for (int nt = 0; nt < 4; nt++) {
            int col = n0 + wn + nt * 16 + l16;
            float bcol = bias[col];
            #pragma unroll
            for (int r = 0; r < 4; r++) {
                int row = m0 + wm + mt * 16 + quad * 4 + r;
                float val = acc[mt][nt][r] + bcol;
                if (col < 512)        qout[(long)row * 512 + col]          = val;
                else if (col < 1024)  kout[(long)row * 512 + (col - 512)]  = val;
                else                  vout[(long)row * 512 + (col - 1024)] = __float2bfloat16(val);
            }
        }
    }
}

// ---------------- attention ----------------

__global__ __launch_bounds__(256) void scores_kernel(
    const float* __restrict__ q, const float* __restrict__ k, float* __restrict__ sc)
{
    __shared__ float ql[512];
    int b = blockIdx.x, tid = threadIdx.x;
    const float* qrow = q + (long)(b * S_ + S_ - 1) * 512;
    ql[tid]       = qrow[tid];
    ql[tid + 256] = qrow[tid + 256];
    __syncthreads();
    int wave = tid >> 6, lane = tid & 63;
    int s0 = blockIdx.y * 32;
    float4 q1 = *(const float4*)&ql[lane * 8];
    float4 q2 = *(const float4*)&ql[lane * 8 + 4];
    for (int s = s0 + wave; s < s0 + 32; s += 4) {
        const float4* kr = (const float4*)(k + ((long)b * S_ + s) * 512);
        float4 x1 = kr[lane * 2], x2 = kr[lane * 2 + 1];
        float acc = x1.x * q1.x + x1.y * q1.y + x1.z * q1.z + x1.w * q1.w
                  + x2.x * q2.x + x2.y * q2.y + x2.z * q2.z + x2.w * q2.w;
        #pragma unroll
        for (int off = 32; off; off >>= 1) acc += __shfl_xor(acc, off);
        if (lane == 0) sc[(long)b * S_ + s] = acc;
    }
}

__global__ __launch_bounds__(256) void softmax_kernel(const float* __restrict__ sc,
                                                      float* __restrict__ attn)
{
    int b = blockIdx.x, tid = threadIdx.x;
    __shared__ float red[256];
    const float* row = sc + (long)b * S_;
    float mx = -1e30f;
    for (int s = tid; s < S_; s += 256) mx = fmaxf(mx, row[s]);
    red[tid] = mx; __syncthreads();
    for (int o = 128; o; o >>= 1) { if (tid < o) red[tid] = fmaxf(red[tid], red[tid + o]); __syncthreads(); }
    mx = red[0]; __syncthreads();
    float sum = 0.f;
    float* arow = attn + (long)b * S_;
    for (int s = tid; s < S_; s += 256) { float e = __expf(row[s] - mx); arow[s] = e; sum += e; }
    red[tid] = sum; __syncthreads();
    for (int o = 128; o; o >>= 1) { if (tid < o) red[tid] += red[tid + o]; __syncthreads(); }
    float inv = 1.0f / red[0];
    for (int s = tid; s < S_; s += 256) arow[s] *= inv;
}

__global__ __launch_bounds__(256) void h_init_kernel(const float* __restrict__ x,
                                                     float* __restrict__ h) {
    int i = blockIdx.x * 256 + threadIdx.x;  // [0, 16*512)
    int b = i >> 9, d = i & 511;
    h[i] = x[(long)(b * S_ + S_ - 1) * 512 + d];
}

__global__ __launch_bounds__(256) void sa_kernel(const __hip_bfloat16* __restrict__ v,
                                                 const float* __restrict__ attn,
                                                 float* __restrict__ h)
{
    int b  = blockIdx.x;
    int d0 = blockIdx.y * 128;   // 4 chunks
    int s0 = blockIdx.z * 512;   // 8 chunks
    int tid = threadIdx.x;
    int dt = (tid & 63) * 2;
    int sg = tid >> 6;
    float a0 = 0.f, a1 = 0.f;
    for (int s = s0 + sg; s < s0 + 512; s += 4) {
        float w = attn[(long)b * S_ + s];
        __hip_bfloat162 vv = *(const __hip_bfloat162*)(v + ((long)(b * S_ + s)) * 512 + d0 + dt);
        float2 vf = __bfloat1622float2(vv);
        a0 += w * vf.x; a1 += w * vf.y;
    }
    atomicAdd(&h[b * 512 + d0 + dt],     a0);
    atomicAdd(&h[b * 512 + d0 + dt + 1], a1);
}

// ---------------- MLP ----------------
// Latency-bound before: 128 blocks (0.5/CU) with 512/2048-iter serial dot loops.
// Now: 512 blocks, each computes 64 outputs with 4-way K-split + LDS reduce.

__global__ __launch_bounds__(256) void mlp1_kernel(const float* __restrict__ h,
    const float* __restrict__ W1, const float* __restrict__ b1, float* __restrict__ h1)
{
    int b  = blockIdx.x;
    int j0 = blockIdx.y * 64;          // 32 chunks over M
    int tid = threadIdx.x;
    int j = tid & 63, kg = tid >> 6;   // 4 k-groups of 128
    __shared__ float hs[512];
    __shared__ float red[256];
    hs[tid]       = h[b * 512 + tid];
    hs[tid + 256] = h[b * 512 + tid + 256];
    __syncthreads();
    const float* wp = W1 + (long)(kg * 128) * M_ + j0 + j;
    float acc = 0.f;
    #pragma unroll 4
    for (int k2 = 0; k2 < 128; k2++) acc += hs[kg * 128 + k2] * wp[(long)k2 * M_];
    red[tid] = acc; __syncthreads();
    if (kg == 0) {
        float val = red[j] + red[64 + j] + red[128 + j] + red[192 + j] + b1[j0 + j];
        h1[(long)b * M_ + j0 + j] = fmaxf(val, 0.f);
    }
}

__global__ __launch_bounds__(256) void mlp2_kernel(const float* __restrict__ h1,
    const float* __restrict__ W2, const float* __restrict__ b2, float* __restrict__ h2)
{
    int b  = blockIdx.x;
    int j0 = blockIdx.y * 64;          // 32 chunks over M
    int tid = threadIdx.x;
    int j = tid & 63, kg = tid >> 6;   // 4 k-groups of 512
    __shared__ float hs[2048];
    __shared__ float red[256];
    for (int t = tid; t < 2048; t += 256) hs[t] = h1[(long)b * M_ + t];
    __syncthreads();
    const float* wp = W2 + (long)(kg * 512) * M_ + j0 + j;
    float acc = 0.f;
    #pragma unroll 4
    for (int k2 = 0; k2 < 512; k2++) acc += hs[kg * 512 + k2] * wp[(long)k2 * M_];
    red[tid] = acc; __syncthreads();
    if (kg == 0) {
        float val = red[j] + red[64 + j] + red[128 + j] + red[192 + j] + b2[j0 + j];
        h2[(long)b * M_ + j0 + j] = fmaxf(val, 0.f);
    }
}

__global__ __launch_bounds__(256) void mlp3_kernel(const float* __restrict__ h2,
    const float* __restrict__ W3, const float* __restrict__ b3, float* __restrict__ out)
{
    int b = blockIdx.x, tid = threadIdx.x;
    __shared__ float red[256];
    float acc = 0.f;
    for (int k2 = tid; k2 < 2048; k2 += 256) acc += h2[(long)b * M_ + k2] * W3[k2];
    red[tid] = acc; __syncthreads();
    for (int o = 128; o; o >>= 1) { if (tid < o) red[tid] += red[tid + o]; __syncthreads(); }
    if (tid == 0) out[b] = red[0] + b3[0];
}

// ---------------- launch ----------------

extern "C" void kernel_launch(void* const* d_in, const int* in_sizes, int n_in,
                              void* d_out, int out_size, void* d_ws, size_t ws_size,
                              hipStream_t stream)
{
    const float* x    = (const float*)d_in[0];
    const float* Wqkv = (const float*)d_in[1];
    const float* bqkv = (const float*)d_in[2];
    const float* W1   = (const float*)d_in[3];
    const float* b1   = (const float*)d_in[4];
    const float* W2   = (const float*)d_in[5];
    const float* b2   = (const float*)d_in[6];
    const float* W3   = (const float*)d_in[7];
    const float* b3   = (const float*)d_in[8];

    float* out  = (float*)d_out;                    // (B,1) = 16 floats
    float* qout = out + 16;                         // (B,S,D)
    float* kout = qout + (size_t)ROWS * 512;        // (B,S,D)

    char* ws = (char*)d_ws;
    size_t off = 0;
    auto alloc = [&](size_t bytes) -> char* {
        char* p = ws + off; off += (bytes + 255) & ~(size_t)255; return p;
    };
    __hip_bfloat16* Xb = (__hip_bfloat16*)alloc((size_t)ROWS * 512 * 2);
    __hip_bfloat16* Wt = (__hip_bfloat16*)alloc((size_t)N3D * 512 * 2);
    __hip_bfloat16* Vb = (__hip_bfloat16*)alloc((size_t)ROWS * 512 * 2);
    float* sc   = (float*)alloc((size_t)B_ * S_ * 4);
    float* attn = (float*)alloc((size_t)B_ * S_ * 4);
    float* h    = (float*)alloc((size_t)B_ * 512 * 4);
    float* h1   = (float*)alloc((size_t)B_ * M_ * 4);
    float* h2   = (float*)alloc((size_t)B_ * M_ * 4);

    hipLaunchKernelGGL(cvt_x_kernel,   dim3(ROWS * 512 / 8 / 256), dim3(256), 0, stream, x, Xb);
    hipLaunchKernelGGL(cvt_w_kernel,   dim3(48, 16),               dim3(256), 0, stream, Wqkv, Wt);
    hipLaunchKernelGGL(h_init_kernel,  dim3(B_ * 512 / 256), dim3(256), 0, stream, x, h);
    hipLaunchKernelGGL(gemm_qkv_kernel, dim3(6144), dim3(256), 0, stream,
                       Xb, Wt, bqkv, qout, kout, Vb);
    hipLaunchKernelGGL(scores_kernel,  dim3(B_, 128), dim3(256), 0, stream, qout, kout, sc);
    hipLaunchKernelGGL(softmax_kernel, dim3(B_),      dim3(256), 0, stream, sc, attn);
    hipLaunchKernelGGL(sa_kernel,      dim3(B_, 4, 8), dim3(256), 0, stream, Vb, attn, h);
    hipLaunchKernelGGL(mlp1_kernel,    dim3(B_, 32), dim3(256), 0, stream, h, W1, b1, h1);
    hipLaunchKernelGGL(mlp2_kernel,    dim3(B_, 32), dim3(256), 0, stream, h1, W2, b2, h2);
    hipLaunchKernelGGL(mlp3_kernel,    dim3(B_),     dim3(256), 0, stream, h2, W3, b3, out);
}

// Round 2
// 693.505 us; speedup vs baseline: 1.0743x; 1.0501x over previous
//
#include <hip/hip_runtime.h>
#include <hip/hip_bf16.h>

#define B_  16
#define S_  4096
#define D_  512
#define M_  2048
#define ROWS (B_ * S_)   // 65536
#define N3D  (3 * D_)    // 1536

typedef __attribute__((ext_vector_type(8))) short bf16x8;
typedef __attribute__((ext_vector_type(4))) float f32x4;

// ---------------- conversions ----------------

__global__ __launch_bounds__(256) void cvt_x_kernel(const float* __restrict__ x,
                                                    __hip_bfloat16* __restrict__ xb) {
    long i = (long)blockIdx.x * 256 + threadIdx.x;   // i in [0, ROWS*D_/8)
    const float4* x4 = (const float4*)x;
    float4 a = x4[2 * i], b = x4[2 * i + 1];
    union { __hip_bfloat16 h[8]; int4 v; } u;
    u.h[0] = __float2bfloat16(a.x); u.h[1] = __float2bfloat16(a.y);
    u.h[2] = __float2bfloat16(a.z); u.h[3] = __float2bfloat16(a.w);
    u.h[4] = __float2bfloat16(b.x); u.h[5] = __float2bfloat16(b.y);
    u.h[6] = __float2bfloat16(b.z); u.h[7] = __float2bfloat16(b.w);
    ((int4*)xb)[i] = u.v;
}

// W_qkv (D x 3D, row-major) -> Wt (3D x D) bf16, transposed (LDS tile transpose).
__global__ __launch_bounds__(256) void cvt_w_kernel(const float* __restrict__ w,
                                                    __hip_bfloat16* __restrict__ wt) {
    __shared__ float t[32][33];
    int n0 = blockIdx.x * 32;
    int k0 = blockIdx.y * 32;
    int c = threadIdx.x & 31, r = threadIdx.x >> 5;
    #pragma unroll
    for (int i = 0; i < 4; i++)
        t[r + 8 * i][c] = w[(long)(k0 + r + 8 * i) * N3D + n0 + c];
    __syncthreads();
    #pragma unroll
    for (int i = 0; i < 4; i++)
        wt[(long)(n0 + r + 8 * i) * 512 + k0 + c] = __float2bfloat16(t[c][r + 8 * i]);
}

// ---------------- qkv GEMM ----------------
// 256x256 tile, BK=32, 8 waves (2Mx4N), 4-deep LDS rotation, counted vmcnt.
// Per K-step: stage Kt j+3 (4x gload16, issue-early) ; 12 ds_read_b128 + 32 MFMA
// (setprio-wrapped) ; s_waitcnt vmcnt(8) lgkmcnt(0) ; s_barrier.  vmcnt never 0
// in the loop: 2 K-tiles of loads stay in flight across every barrier (T4).
// LDS swizzle: linear dest + inverse-swizzled global SOURCE (involution
// chunk ^= (row>>1)&3 on 16B chunks within each 64B row) + same XOR on ds_read
// -> measured 0 bank conflicts with identical geometry in round 1.

__device__ __forceinline__ void gload16(const __hip_bfloat16* g, __hip_bfloat16* l) {
    __builtin_amdgcn_global_load_lds(
        (const __attribute__((address_space(1))) unsigned int*)g,
        (__attribute__((address_space(3))) unsigned int*)l, 16, 0, 0);
}

__global__ __launch_bounds__(512, 2) void gemm_qkv_kernel(
    const __hip_bfloat16* __restrict__ Xb,
    const __hip_bfloat16* __restrict__ Wt,
    const float* __restrict__ bias,
    float* __restrict__ qout, float* __restrict__ kout,
    __hip_bfloat16* __restrict__ vout)
{
    // 4 rotation buffers, each 256 rows x 32 cols bf16 (16 KiB) per operand.
    __shared__ __attribute__((aligned(128))) __hip_bfloat16 As[4 * 8192];
    __shared__ __attribute__((aligned(128))) __hip_bfloat16 Bs[4 * 8192];

    const int tid  = threadIdx.x;
    const int w    = tid >> 6, lane = tid & 63;
    const int wr   = w >> 2, wc = w & 3;           // 2 x 4 wave grid
    const int quad = lane >> 4, l16 = lane & 15;

    // bijective XCD swizzle: 1536 blocks = 192/XCD; n fastest within an XCD.
    int bid = blockIdx.x;
    int swz = (bid & 7) * 192 + (bid >> 3);
    const int m0 = (swz / 6) * 256;
    const int n0 = (swz % 6) * 256;

    // Staging geometry: one K-tile of one operand = 256x32x2B = 16 KiB
    // = 2 gload16 issues x 8 waves x 64 lanes x 16 B.
    const int beta0 = w * 1024 + lane * 16;                       // issue-0 LDS byte
    const int row0  = beta0 >> 6;                                 // 0..127
    const int cb0   = (beta0 & 63) ^ (((beta0 >> 7) & 3) << 4);   // swizzled src byte
    const int e0    = beta0 >> 1;                                 // LDS elem offset
    const int e1    = e0 + 4096;                                  // issue 1 (rows +128)

    const __hip_bfloat16* aS0 = Xb + (long)(m0 + row0) * 512 + (cb0 >> 1);
    const __hip_bfloat16* aS1 = aS0 + (long)128 * 512;
    const __hip_bfloat16* bS0 = Wt + (long)(n0 + row0) * 512 + (cb0 >> 1);
    const __hip_bfloat16* bS1 = bS0 + (long)128 * 512;

    // ds_read fragment offsets (elements), same XOR as the staged source.
    int aoff[8], boff[4];
    #pragma unroll
    for (int mt = 0; mt < 8; mt++) {
        int r = wr * 128 + mt * 16 + l16;
        aoff[mt] = r * 32 + ((quad ^ ((r >> 1) & 3)) << 3);
    }
    #pragma unroll
    for (int nt = 0; nt < 4; nt++) {
        int r = wc * 64 + nt * 16 + l16;
        boff[nt] = r * 32 + ((quad ^ ((r >> 1) & 3)) << 3);
    }

    f32x4 acc[8][4] = {};

    auto stage = [&](int kt) {
        int kb = (kt & 3) * 8192;
        long ko = (long)kt * 32;
        gload16(aS0 + ko, As + kb + e0);
        gload16(aS1 + ko, As + kb + e1);
        gload16(bS0 + ko, Bs + kb + e0);
        gload16(bS1 + ko, Bs + kb + e1);
    };
    auto compute = [&](int j) {
        const __hip_bfloat16* Ab = As + (j & 3) * 8192;
        const __hip_bfloat16* Bb = Bs + (j & 3) * 8192;
        bf16x8 af[8], bf[4];
        #pragma unroll
        for (int mt = 0; mt < 8; mt++) af[mt] = *(const bf16x8*)(Ab + aoff[mt]);
        #pragma unroll
        for (int nt = 0; nt < 4; nt++) bf[nt] = *(const bf16x8*)(Bb + boff[nt]);
        __builtin_amdgcn_s_setprio(1);
        #pragma unroll
        for (int mt = 0; mt < 8; mt++)
            #pragma unroll
            for (int nt = 0; nt < 4; nt++)
                acc[mt][nt] = __builtin_amdgcn_mfma_f32_16x16x32_bf16(
                    af[mt], bf[nt], acc[mt][nt], 0, 0, 0);
        __builtin_amdgcn_s_setprio(0);
    };

    // Prologue: 3 K-tiles in flight; confirm Kt0 (12 outstanding -> vmcnt(8)).
    stage(0); stage(1); stage(2);
    asm volatile("s_waitcnt vmcnt(8)" ::: "memory");
    asm volatile("s_barrier" ::: "memory");

    // Steady state: end-of-step-(j-1) wait confirms Kt j (12 outstanding -> 8).
    // lgkmcnt(0) retires this step's ds_reads before the barrier, making the
    // buffer safe for step j+1's overwrite of buf[(j+4)&3] == buf[j&3].
    #pragma unroll 1
    for (int j = 0; j < 13; ++j) {
        stage(j + 3);
        compute(j);
        asm volatile("s_waitcnt vmcnt(8) lgkmcnt(0)" ::: "memory");
        asm volatile("s_barrier" ::: "memory");
    }
    compute(13);
    asm volatile("s_waitcnt vmcnt(4) lgkmcnt(0)" ::: "memory");
    asm volatile("s_barrier" ::: "memory");
    compute(14);
    asm volatile("s_waitcnt vmcnt(0) lgkmcnt(0)" ::: "memory");
    asm volatile("s_barrier" ::: "memory");
    compute(15);

    // Epilogue: scatter q/k (fp32) and v (bf16).
    #pragma unroll
    for (int mt = 0; mt < 8; mt++) {
        #pragma unroll
        for (int nt = 0; nt < 4; nt++) {
            int col = n0 + wc * 64 + nt * 16 + l16;
            float bcol = bias[col];
            #pragma unroll
            for (int r = 0; r < 4; r++) {
                int row = m0 + wr * 128 + mt * 16 + quad * 4 + r;
                float val = acc[mt][nt][r] + bcol;
                if (col < 512)        qout[(long)row * 512 + col]          = val;
                else if (col < 1024)  kout[(long)row * 512 + (col - 512)]  = val;
                else                  vout[(long)row * 512 + (col - 1024)] = __float2bfloat16(val);
            }
        }
    }
}

// ---------------- attention ----------------

__global__ __launch_bounds__(256) void scores_kernel(
    const float* __restrict__ q, const float* __restrict__ k, float* __restrict__ sc)
{
    __shared__ float ql[512];
    int b = blockIdx.x, tid = threadIdx.x;
    const float* qrow = q + (long)(b * S_ + S_ - 1) * 512;
    ql[tid]       = qrow[tid];
    ql[tid + 256] = qrow[tid + 256];
    __syncthreads();
    int wave = tid >> 6, lane = tid & 63;
    int s0 = blockIdx.y * 32;
    float4 q1 = *(const float4*)&ql[lane * 8];
    float4 q2 = *(const float4*)&ql[lane * 8 + 4];
    for (int s = s0 + wave; s < s0 + 32; s += 4) {
        const float4* kr = (const float4*)(k + ((long)b * S_ + s) * 512);
        float4 x1 = kr[lane * 2], x2 = kr[lane * 2 + 1];
        float acc = x1.x * q1.x + x1.y * q1.y + x1.z * q1.z + x1.w * q1.w
                  + x2.x * q2.x + x2.y * q2.y + x2.z * q2.z + x2.w * q2.w;
        #pragma unroll
        for (int off = 32; off; off >>= 1) acc += __shfl_xor(acc, off);
        if (lane == 0) sc[(long)b * S_ + s] = acc;
    }
}

__global__ __launch_bounds__(256) void softmax_kernel(const float* __restrict__ sc,
                                                      float* __restrict__ attn)
{
    int b = blockIdx.x, tid = threadIdx.x;
    __shared__ float red[256];
    const float* row = sc + (long)b * S_;
    float mx = -1e30f;
    for (int s = tid; s < S_; s += 256) mx = fmaxf(mx, row[s]);
    red[tid] = mx; __syncthreads();
    for (int o = 128; o; o >>= 1) { if (tid < o) red[tid] = fmaxf(red[tid], red[tid + o]); __syncthreads(); }
    mx = red[0]; __syncthreads();
    float sum = 0.f;
    float* arow = attn + (long)b * S_;
    for (int s = tid; s < S_; s += 256) { float e = __expf(row[s] - mx); arow[s] = e; sum += e; }
    red[tid] = sum; __syncthreads();
    for (int o = 128; o; o >>= 1) { if (tid < o) red[tid] += red[tid + o]; __syncthreads(); }
    float inv = 1.0f / red[0];
    for (int s = tid; s < S_; s += 256) arow[s] *= inv;
}

__global__ __launch_bounds__(256) void h_init_kernel(const float* __restrict__ x,
                                                     float* __restrict__ h) {
    int i = blockIdx.x * 256 + threadIdx.x;  // [0, 16*512)
    int b = i >> 9, d = i & 511;
    h[i] = x[(long)(b * S_ + S_ - 1) * 512 + d];
}

__global__ __launch_bounds__(256) void sa_kernel(const __hip_bfloat16* __restrict__ v,
                                                 const float* __restrict__ attn,
                                                 float* __restrict__ h)
{
    int b  = blockIdx.x;
    int d0 = blockIdx.y * 128;   // 4 chunks
    int s0 = blockIdx.z * 512;   // 8 chunks
    int tid = threadIdx.x;
    int dt = (tid & 63) * 2;
    int sg = tid >> 6;
    float a0 = 0.f, a1 = 0.f;
    for (int s = s0 + sg; s < s0 + 512; s += 4) {
        float w = attn[(long)b * S_ + s];
        __hip_bfloat162 vv = *(const __hip_bfloat162*)(v + ((long)(b * S_ + s)) * 512 + d0 + dt);
        float2 vf = __bfloat1622float2(vv);
        a0 += w * vf.x; a1 += w * vf.y;
    }
    atomicAdd(&h[b * 512 + d0 + dt],     a0);
    atomicAdd(&h[b * 512 + d0 + dt + 1], a1);
}

// ---------------- MLP ----------------
// float4 weight loads (16 B/lane) + 8-way K-split, 256 blocks.

__global__ __launch_bounds__(256) void mlp1_kernel(const float* __restrict__ h,
    const float* __restrict__ W1, const float* __restrict__ b1, float* __restrict__ h1)
{
    int b  = blockIdx.x;
    int j0 = blockIdx.y * 128;         // 16 chunks over M
    int tid = threadIdx.x;
    int jl = tid & 31, kg = tid >> 5;  // 8 k-groups of 64
    __shared__ float hs[512];
    __shared__ float4 red[256];
    hs[tid]       = h[b * 512 + tid];
    hs[tid + 256] = h[b * 512 + tid + 256];
    __syncthreads();
    float4 acc = {0.f, 0.f, 0.f, 0.f};
    #pragma unroll 4
    for (int k2 = 0; k2 < 64; k2++) {
        float hv = hs[kg * 64 + k2];
        float4 wv = *(const float4*)&W1[(long)(kg * 64 + k2) * M_ + j0 + jl * 4];
        acc.x += hv * wv.x; acc.y += hv * wv.y; acc.z += hv * wv.z; acc.w += hv * wv.w;
    }
    red[tid] = acc; __syncthreads();
    if (tid < 32) {
        float4 s = red[tid];
        #pragma unroll
        for (int g = 1; g < 8; g++) {
            float4 t = red[g * 32 + tid];
            s.x += t.x; s.y += t.y; s.z += t.z; s.w += t.w;
        }
        float4 bb = *(const float4*)&b1[j0 + tid * 4];
        s.x = fmaxf(s.x + bb.x, 0.f); s.y = fmaxf(s.y + bb.y, 0.f);
        s.z = fmaxf(s.z + bb.z, 0.f); s.w = fmaxf(s.w + bb.w, 0.f);
        *(float4*)&h1[(long)b * M_ + j0 + tid * 4] = s;
    }
}

__global__ __launch_bounds__(256) void mlp2_kernel(const float* __restrict__ h1,
    const float* __restrict__ W2, const float* __restrict__ b2, float* __restrict__ h2)
{
    int b  = blockIdx.x;
    int j0 = blockIdx.y * 128;         // 16 chunks over M
    int tid = threadIdx.x;
    int jl = tid & 31, kg = tid >> 5;  // 8 k-groups of 256
    __shared__ float hs[2048];
    __shared__ float4 red[256];
    for (int t = tid; t < 2048; t += 256) hs[t] = h1[(long)b * M_ + t];
    __syncthreads();
    float4 acc = {0.f, 0.f, 0.f, 0.f};
    #pragma unroll 4
    for (int k2 = 0; k2 < 256; k2++) {
        float hv = hs[kg * 256 + k2];
        float4 wv = *(const float4*)&W2[(long)(kg * 256 + k2) * M_ + j0 + jl * 4];
        acc.x += hv * wv.x; acc.y += hv * wv.y; acc.z += hv * wv.z; acc.w += hv * wv.w;
    }
    red[tid] = acc; __syncthreads();
    if (tid < 32) {
        float4 s = red[tid];
        #pragma unroll
        for (int g = 1; g < 8; g++) {
            float4 t = red[g * 32 + tid];
            s.x += t.x; s.y += t.y; s.z += t.z; s.w += t.w;
        }
        float4 bb = *(const float4*)&b2[j0 + tid * 4];
        s.x = fmaxf(s.x + bb.x, 0.f); s.y = fmaxf(s.y + bb.y, 0.f);
        s.z = fmaxf(s.z + bb.z, 0.f); s.w = fmaxf(s.w + bb.w, 0.f);
        *(float4*)&h2[(long)b * M_ + j0 + tid * 4] = s;
    }
}

__global__ __launch_bounds__(256) void mlp3_kernel(const float* __restrict__ h2,
    const float* __restrict__ W3, const float* __restrict__ b3, float* __restrict__ out)
{
    int b = blockIdx.x, tid = threadIdx.x;
    __shared__ float red[256];
    float acc = 0.f;
    for (int k2 = tid; k2 < 2048; k2 += 256) acc += h2[(long)b * M_ + k2] * W3[k2];
    red[tid] = acc; __syncthreads();
    for (int o = 128; o; o >>= 1) { if (tid < o) red[tid] += red[tid + o]; __syncthreads(); }
    if (tid == 0) out[b] = red[0] + b3[0];
}

// ---------------- launch ----------------

extern "C" void kernel_launch(void* const* d_in, const int* in_sizes, int n_in,
                              void* d_out, int out_size, void* d_ws, size_t ws_size,
                              hipStream_t stream)
{
    const float* x    = (const float*)d_in[0];
    const float* Wqkv = (const float*)d_in[1];
    const float* bqkv = (const float*)d_in[2];
    const float* W1   = (const float*)d_in[3];
    const float* b1   = (const float*)d_in[4];
    const float* W2   = (const float*)d_in[5];
    const float* b2   = (const float*)d_in[6];
    const float* W3   = (const float*)d_in[7];
    const float* b3   = (const float*)d_in[8];

    float* out  = (float*)d_out;                    // (B,1) = 16 floats
    float* qout = out + 16;                         // (B,S,D)
    float* kout = qout + (size_t)ROWS * 512;        // (B,S,D)

    char* ws = (char*)d_ws;
    size_t off = 0;
    auto alloc = [&](size_t bytes) -> char* {
        char* p = ws + off; off += (bytes + 255) & ~(size_t)255; return p;
    };
    __hip_bfloat16* Xb = (__hip_bfloat16*)alloc((size_t)ROWS * 512 * 2);
    __hip_bfloat16* Wt = (__hip_bfloat16*)alloc((size_t)N3D * 512 * 2);
    __hip_bfloat16* Vb = (__hip_bfloat16*)alloc((size_t)ROWS * 512 * 2);
    float* sc   = (float*)alloc((size_t)B_ * S_ * 4);
    float* attn = (float*)alloc((size_t)B_ * S_ * 4);
    float* h    = (float*)alloc((size_t)B_ * 512 * 4);
    float* h1   = (float*)alloc((size_t)B_ * M_ * 4);
    float* h2   = (float*)alloc((size_t)B_ * M_ * 4);

    hipLaunchKernelGGL(cvt_x_kernel,   dim3(ROWS * 512 / 8 / 256), dim3(256), 0, stream, x, Xb);
    hipLaunchKernelGGL(cvt_w_kernel,   dim3(48, 16),               dim3(256), 0, stream, Wqkv, Wt);
    hipLaunchKernelGGL(h_init_kernel,  dim3(B_ * 512 / 256), dim3(256), 0, stream, x, h);
    hipLaunchKernelGGL(gemm_qkv_kernel, dim3(1536), dim3(512), 0, stream,
                       Xb, Wt, bqkv, qout, kout, Vb);
    hipLaunchKernelGGL(scores_kernel,  dim3(B_, 128), dim3(256), 0, stream, qout, kout, sc);
    hipLaunchKernelGGL(softmax_kernel, dim3(B_),      dim3(256), 0, stream, sc, attn);
    hipLaunchKernelGGL(sa_kernel,      dim3(B_, 4, 8), dim3(256), 0, stream, Vb, attn, h);
    hipLaunchKernelGGL(mlp1_kernel,    dim3(B_, 16), dim3(256), 0, stream, h, W1, b1, h1);
    hipLaunchKernelGGL(mlp2_kernel,    dim3(B_, 16), dim3(256), 0, stream, h1, W2, b2, h2);
    hipLaunchKernelGGL(mlp3_kernel,    dim3(B_),     dim3(256), 0, stream, h2, W3, b3, out);
}